// Round 1
// baseline (108.896 us; speedup 1.0000x reference)
//
#include <hip/hip_runtime.h>
#include <hip/hip_bf16.h>
#include <cstdint>

#define S_LEN  8192
#define IN_DIM 512
#define D_DIM  64
#define BATCH  2
#define ROWS   (BATCH * S_LEN)  // 16384

// ws layout (float offsets)
#define OFF_E1 0
#define OFF_Y2 (ROWS * D_DIM)          // 1048576
#define OFF_Y3 (2 * ROWS * D_DIM)      // 2097152
#define OFF_M  (3 * ROWS * D_DIM)      // 3145728  [B][64][64]
#define OFF_U  (OFF_M + BATCH * D_DIM * D_DIM)  // [B][64]
#define OFF_V  (OFF_U + BATCH * D_DIM)          // [B][64]
#define OFF_N2 (OFF_V + BATCH * D_DIM)          // [B][64][512]

// ---------------------------------------------------------------------------
// K1: Y_w = x @ W_w^T  (+ b1 for w==0), w in {0,1,2} selects W1/W2/W3.
// Tall-skinny GEMM: M=16384, N=64, K=512. BM=64, BN=64, BK=32.
// 256 threads, thread tile 4x4. grid (256, 3).
// ---------------------------------------------------------------------------
__global__ __launch_bounds__(256) void k_proj(
    const float* __restrict__ x,
    const float* __restrict__ W1, const float* __restrict__ b1,
    const float* __restrict__ W2, const float* __restrict__ W3,
    float* __restrict__ ws)
{
    const int w = blockIdx.y;
    const float* Wp = (w == 0) ? W1 : (w == 1) ? W2 : W3;
    float* Yp = ws + ((w == 0) ? OFF_E1 : (w == 1) ? OFF_Y2 : OFF_Y3);
    const int row0 = blockIdx.x * 64;

    __shared__ float Xs[32][68];  // [k][row], padded
    __shared__ float Ws[32][68];  // [k][d],   padded

    const int tid = threadIdx.x;
    const int tr = tid >> 4;      // 0..15
    const int tc = tid & 15;      // 0..15

    float acc[4][4];
#pragma unroll
    for (int i = 0; i < 4; ++i)
#pragma unroll
        for (int j = 0; j < 4; ++j) acc[i][j] = 0.f;

    for (int kt = 0; kt < IN_DIM; kt += 32) {
        // stage X tile [64 rows][32 k] transposed; 512 float4, 2/thread
#pragma unroll
        for (int t = 0; t < 2; ++t) {
            int idx = tid + t * 256;     // 0..511
            int r   = idx >> 3;          // 0..63
            int c4  = idx & 7;           // 0..7
            float4 v = *(const float4*)(x + (size_t)(row0 + r) * IN_DIM + kt + c4 * 4);
            Xs[c4 * 4 + 0][r] = v.x; Xs[c4 * 4 + 1][r] = v.y;
            Xs[c4 * 4 + 2][r] = v.z; Xs[c4 * 4 + 3][r] = v.w;
            float4 wv = *(const float4*)(Wp + (size_t)r * IN_DIM + kt + c4 * 4);
            Ws[c4 * 4 + 0][r] = wv.x; Ws[c4 * 4 + 1][r] = wv.y;
            Ws[c4 * 4 + 2][r] = wv.z; Ws[c4 * 4 + 3][r] = wv.w;
        }
        __syncthreads();
#pragma unroll 8
        for (int kk = 0; kk < 32; ++kk) {
            float4 a = *(const float4*)&Xs[kk][tr * 4];
            float4 b = *(const float4*)&Ws[kk][tc * 4];
            float av[4] = {a.x, a.y, a.z, a.w};
            float bv[4] = {b.x, b.y, b.z, b.w};
#pragma unroll
            for (int i = 0; i < 4; ++i)
#pragma unroll
                for (int j = 0; j < 4; ++j) acc[i][j] += av[i] * bv[j];
        }
        __syncthreads();
    }

    float4 bias = make_float4(0.f, 0.f, 0.f, 0.f);
    if (w == 0) bias = *(const float4*)(b1 + tc * 4);
#pragma unroll
    for (int i = 0; i < 4; ++i) {
        float4 o;
        o.x = acc[i][0] + bias.x; o.y = acc[i][1] + bias.y;
        o.z = acc[i][2] + bias.z; o.w = acc[i][3] + bias.w;
        *(float4*)(Yp + (size_t)(row0 + tr * 4 + i) * D_DIM + tc * 4) = o;
    }
}

// ---------------------------------------------------------------------------
// K1b: M[b] += Y2[chunk]^T @ Y3[chunk]; u += colsum(Y2), v += colsum(Y3).
// grid (64 splits, B), 256 threads, thread tile 4x4 of the 64x64 M.
// Atomic accumulation into zeroed ws (M, u, v).
// ---------------------------------------------------------------------------
__global__ __launch_bounds__(256) void k_M(float* __restrict__ ws)
{
    const int split = blockIdx.x;   // 0..63 -> 128 rows each
    const int b     = blockIdx.y;
    const float* Y2 = ws + OFF_Y2 + (size_t)b * S_LEN * D_DIM;
    const float* Y3 = ws + OFF_Y3 + (size_t)b * S_LEN * D_DIM;

    __shared__ float Y2s[64][68];
    __shared__ float Y3s[64][68];

    const int tid = threadIdx.x;
    const int tr = tid >> 4, tc = tid & 15;

    float acc[4][4];
#pragma unroll
    for (int i = 0; i < 4; ++i)
#pragma unroll
        for (int j = 0; j < 4; ++j) acc[i][j] = 0.f;
    float uacc = 0.f, vacc = 0.f;

    for (int sub = 0; sub < 2; ++sub) {
        const int row0 = split * 128 + sub * 64;
#pragma unroll
        for (int t = 0; t < 4; ++t) {
            int idx = tid + t * 256;   // 0..1023 (1024 float4)
            int r   = idx >> 4;        // 0..63
            int c4  = idx & 15;        // 0..15
            *(float4*)&Y2s[r][c4 * 4] = *(const float4*)(Y2 + (size_t)(row0 + r) * D_DIM + c4 * 4);
            *(float4*)&Y3s[r][c4 * 4] = *(const float4*)(Y3 + (size_t)(row0 + r) * D_DIM + c4 * 4);
        }
        __syncthreads();
#pragma unroll 8
        for (int r = 0; r < 64; ++r) {
            float4 a = *(const float4*)&Y2s[r][tr * 4];
            float4 bv = *(const float4*)&Y3s[r][tc * 4];
            float av[4] = {a.x, a.y, a.z, a.w};
            float bw[4] = {bv.x, bv.y, bv.z, bv.w};
#pragma unroll
            for (int i = 0; i < 4; ++i)
#pragma unroll
                for (int j = 0; j < 4; ++j) acc[i][j] += av[i] * bw[j];
        }
        if (tid < 64) {
#pragma unroll 16
            for (int r = 0; r < 64; ++r) uacc += Y2s[r][tid];
        } else if (tid < 128) {
#pragma unroll 16
            for (int r = 0; r < 64; ++r) vacc += Y3s[r][tid - 64];
        }
        __syncthreads();
    }

    float* M = ws + OFF_M + b * D_DIM * D_DIM;
#pragma unroll
    for (int i = 0; i < 4; ++i)
#pragma unroll
        for (int j = 0; j < 4; ++j)
            atomicAdd(&M[(tr * 4 + i) * D_DIM + tc * 4 + j], acc[i][j]);
    if (tid < 64)       atomicAdd(ws + OFF_U + b * D_DIM + tid, uacc);
    else if (tid < 128) atomicAdd(ws + OFF_V + b * D_DIM + tid - 64, vacc);
}

// ---------------------------------------------------------------------------
// K2: finalize M with bias terms; N2 = M @ WO^T  ([64,64]@[64,512]->[64,512]).
// grid (8 col-blocks, B), 256 threads.
// ---------------------------------------------------------------------------
__global__ __launch_bounds__(256) void k_N2(
    const float* __restrict__ b2, const float* __restrict__ b3,
    const float* __restrict__ WO, float* __restrict__ ws)
{
    const int jb = blockIdx.x;   // 0..7
    const int b  = blockIdx.y;

    __shared__ float Ms[64][68];
    __shared__ float WOs[64][68];
    __shared__ float us[64], vs[64];

    const int tid = threadIdx.x;
    const float* M = ws + OFF_M + b * D_DIM * D_DIM;
#pragma unroll
    for (int t = 0; t < 16; ++t) {
        int e = t * 256 + tid;
        Ms[e >> 6][e & 63] = M[e];
    }
    if (tid < 64)       us[tid]      = ws[OFF_U + b * D_DIM + tid];
    else if (tid < 128) vs[tid - 64] = ws[OFF_V + b * D_DIM + tid - 64];
    __syncthreads();
    // M += u b3^T + b2 v^T + S b2 b3^T   (affine-bias cross terms)
#pragma unroll
    for (int t = 0; t < 16; ++t) {
        int e = t * 256 + tid;
        int d2 = e >> 6, d3 = e & 63;
        Ms[d2][d3] += us[d2] * b3[d3] + b2[d2] * vs[d3] + (float)S_LEN * b2[d2] * b3[d3];
    }
    // stage WO tile: rows j0..j0+63 of [512,64]
    const int j0 = jb * 64;
#pragma unroll
    for (int t = 0; t < 4; ++t) {
        int idx = tid + t * 256;
        int r = idx >> 4, c4 = idx & 15;
        *(float4*)&WOs[r][c4 * 4] = *(const float4*)(WO + (size_t)(j0 + r) * D_DIM + c4 * 4);
    }
    __syncthreads();

    const int tr = tid >> 4, tc = tid & 15;
    float acc[4][4];
#pragma unroll
    for (int i = 0; i < 4; ++i)
#pragma unroll
        for (int j = 0; j < 4; ++j) acc[i][j] = 0.f;
#pragma unroll 8
    for (int d = 0; d < 64; ++d) {
        float av[4], bw[4];
#pragma unroll
        for (int i = 0; i < 4; ++i) av[i] = Ms[tr * 4 + i][d];
#pragma unroll
        for (int j = 0; j < 4; ++j) bw[j] = WOs[tc * 4 + j][d];
#pragma unroll
        for (int i = 0; i < 4; ++i)
#pragma unroll
            for (int j = 0; j < 4; ++j) acc[i][j] += av[i] * bw[j];
    }
    float* N2 = ws + OFF_N2 + b * D_DIM * IN_DIM;
#pragma unroll
    for (int i = 0; i < 4; ++i) {
        float4 o = make_float4(acc[i][0], acc[i][1], acc[i][2], acc[i][3]);
        *(float4*)(N2 + (size_t)(tr * 4 + i) * IN_DIM + j0 + tc * 4) = o;
    }
}

// ---------------------------------------------------------------------------
// K3: out = sigmoid(e1 @ N2 + bO).  M=16384 rows, N=512, K=64.
// 32 rows/block, grid 512, 256 threads, thread tile 8 rows x 8 cols.
// ---------------------------------------------------------------------------
__global__ __launch_bounds__(256) void k_out(
    const float* __restrict__ bO, float* __restrict__ out,
    const float* __restrict__ ws)
{
    const int row0 = blockIdx.x * 32;
    const int b    = row0 >> 13;  // /8192
    const float* e1 = ws + OFF_E1;
    const float* N2 = ws + OFF_N2 + (size_t)b * D_DIM * IN_DIM;

    __shared__ float e1s[32][68];
    const int tid = threadIdx.x;
#pragma unroll
    for (int t = 0; t < 2; ++t) {
        int idx = tid + t * 256;   // 512 float4
        int r = idx >> 4, c4 = idx & 15;
        *(float4*)&e1s[r][c4 * 4] = *(const float4*)(e1 + (size_t)(row0 + r) * D_DIM + c4 * 4);
    }
    __syncthreads();

    const int tr = tid >> 6;   // 0..3
    const int tc = tid & 63;   // 0..63
    const int r0 = tr * 8;

    float acc[8][8];
#pragma unroll
    for (int i = 0; i < 8; ++i)
#pragma unroll
        for (int j = 0; j < 8; ++j) acc[i][j] = 0.f;

#pragma unroll 4
    for (int k = 0; k < D_DIM; ++k) {
        float4 na = *(const float4*)(N2 + (size_t)k * IN_DIM + tc * 4);
        float4 nb = *(const float4*)(N2 + (size_t)k * IN_DIM + 256 + tc * 4);
        float bv[8] = {na.x, na.y, na.z, na.w, nb.x, nb.y, nb.z, nb.w};
#pragma unroll
        for (int i = 0; i < 8; ++i) {
            float a = e1s[r0 + i][k];
#pragma unroll
            for (int j = 0; j < 8; ++j) acc[i][j] += a * bv[j];
        }
    }

    float4 bOa = *(const float4*)(bO + tc * 4);
    float4 bOb = *(const float4*)(bO + 256 + tc * 4);
    float ba[8] = {bOa.x, bOa.y, bOa.z, bOa.w, bOb.x, bOb.y, bOb.z, bOb.w};
#pragma unroll
    for (int i = 0; i < 8; ++i) {
        const int row = row0 + r0 + i;
        float o[8];
#pragma unroll
        for (int j = 0; j < 8; ++j) {
            float p = acc[i][j] + ba[j];
            o[j] = 1.f / (1.f + __expf(-p));
        }
        *(float4*)(out + (size_t)row * IN_DIM + tc * 4)       = make_float4(o[0], o[1], o[2], o[3]);
        *(float4*)(out + (size_t)row * IN_DIM + 256 + tc * 4) = make_float4(o[4], o[5], o[6], o[7]);
    }
}

// ---------------------------------------------------------------------------
extern "C" void kernel_launch(void* const* d_in, const int* in_sizes, int n_in,
                              void* d_out, int out_size, void* d_ws, size_t ws_size,
                              hipStream_t stream)
{
    const float* x  = (const float*)d_in[0];
    const float* W1 = (const float*)d_in[1];
    const float* b1 = (const float*)d_in[2];
    const float* W2 = (const float*)d_in[3];
    const float* b2 = (const float*)d_in[4];
    const float* W3 = (const float*)d_in[5];
    const float* b3 = (const float*)d_in[6];
    const float* WO = (const float*)d_in[7];
    const float* bO = (const float*)d_in[8];
    float* out = (float*)d_out;
    float* ws  = (float*)d_ws;

    // zero the atomic accumulators (M, u, v)
    hipMemsetAsync(ws + OFF_M, 0,
                   (size_t)(BATCH * D_DIM * D_DIM + 2 * BATCH * D_DIM) * sizeof(float),
                   stream);

    k_proj<<<dim3(ROWS / 64, 3), 256, 0, stream>>>(x, W1, b1, W2, W3, ws);
    k_M   <<<dim3(64, BATCH),    256, 0, stream>>>(ws);
    k_N2  <<<dim3(8, BATCH),     256, 0, stream>>>(b2, b3, WO, ws);
    k_out <<<dim3(ROWS / 32),    256, 0, stream>>>(bO, out, ws);
}